// Round 7
// baseline (739.665 us; speedup 1.0000x reference)
//
#include <hip/hip_runtime.h>
#include <math.h>

#define NB 16
#define SS 2048
#define DQ 128
#define SCALE 0.08838834764831845f  // 1/sqrt(128)

typedef __bf16 bf16x8 __attribute__((ext_vector_type(8)));
typedef unsigned short ushort8_t __attribute__((ext_vector_type(8)));
typedef float floatx4 __attribute__((ext_vector_type(4)));
typedef unsigned long long u64;

// fp32 -> bf16 round-to-nearest-even (finite randn inputs; no NaN path)
__device__ __forceinline__ unsigned short f2bf(float x) {
  unsigned int u = __float_as_uint(x);
  u += 0x7fffu + ((u >> 16) & 1u);
  return (unsigned short)(u >> 16);
}
union FragU { ushort8_t u; bf16x8 b; };
__device__ __forceinline__ bf16x8 ld_frag(const unsigned short* p) {
  FragU t; t.u = *(const ushort8_t*)p; return t.b;
}
__device__ __forceinline__ floatx4 mfma16(bf16x8 a, bf16x8 b, floatx4 c) {
  return __builtin_amdgcn_mfma_f32_16x16x32_bf16(a, b, c, 0, 0, 0);
}

// LDS-only barrier: waits DS ops, leaves global loads (vmcnt) IN FLIGHT.
__device__ __forceinline__ void bar_lds() {
  asm volatile("s_waitcnt lgkmcnt(0)\n\ts_barrier" ::: "memory");
}

// d_out scratch per batch b: rows 16..31 = colsum accumulator; rows
// 64m..64m+15 = replicated Linv strips (combine_linv).
// d_ws layout (32 MiB): [0,8Mi) Mbits u64; [8,16Mi) Qf; [16,24Mi) Kf;
// [24,32Mi) Vtf — all fragment-ordered bf16:
//  Qf[b][t=q/64][w=(q%64)/16][i=d/32][l15=q%16][quad=(d%32)/8][e=d%8]
//  Kf[b][t=k/64][s=(k%64)/16][i=d/32][l15=k%16][quad][e]      (A-frag order)
//  Vtf[b][t=k/64][j=d/16][c=(k%64)/32][l15=d%16][quad=(k%32)/8][e=k%8]
// One 64-tile = 8192 shorts = 16 KB; a wave's frag load = 1 KB contiguous.

// ---------------------------------------------------------------------------
__global__ void zero_accum(float* __restrict__ O) {
  float* p = O + (size_t)blockIdx.x * SS * DQ + 16 * DQ;
#pragma unroll
  for (int i = 0; i < 8; ++i) p[threadIdx.x + 256 * i] = 0.f;
}

// ---------------------------------------------------------------------------
// Compress mask: 268 MB int32 -> 8 MB bit-words (verified round 6).
// ---------------------------------------------------------------------------
__global__ __launch_bounds__(256) void compress_mask(
    const int* __restrict__ M, u64* __restrict__ Mb)
{
  const int b = blockIdx.x;
  const int q = blockIdx.y * 4 + (threadIdx.x >> 6);
  const int lane = threadIdx.x & 63;

  const int* row = M + ((size_t)b * SS + q) * SS;
  int v[32];
#pragma unroll
  for (int kt = 0; kt < 32; ++kt) v[kt] = row[kt * 64 + lane];

  u64 w = 0;
#pragma unroll
  for (int kt = 0; kt < 32; ++kt) {
    u64 bal = __ballot(v[kt] != 0);
    if (lane == kt) w = bal;
  }
  u64* orow = Mb + ((size_t)b * SS + q) * 32;
  if (lane < 32) orow[lane] = w;
}

// ---------------------------------------------------------------------------
// Cast Q and K (z=0: Q->Qf, z=1: K->Kf) into fragment-ordered bf16.
// grid (NB, 32, 2), 256 thr. Coalesced 1KB fragment-group writes.
// ---------------------------------------------------------------------------
__global__ __launch_bounds__(256) void cast_qk(
    const float* __restrict__ Q, const float* __restrict__ K,
    unsigned short* __restrict__ Qf, unsigned short* __restrict__ Kf)
{
  const int b = blockIdx.x, t = blockIdx.y;
  const float* src = (blockIdx.z ? K : Q) + ((size_t)b * SS + t * 64) * DQ;
  unsigned short* dst = (blockIdx.z ? Kf : Qf) + ((size_t)b * 32 + t) * 8192;
  const int tid = threadIdx.x;
  const int w16 = tid >> 6, l15 = (tid >> 2) & 15, quad = tid & 3;
  const float* row = src + (size_t)(16 * w16 + l15) * DQ;
#pragma unroll
  for (int i = 0; i < 4; ++i) {
    float4 a = *(const float4*)(row + 32 * i + quad * 8);
    float4 c = *(const float4*)(row + 32 * i + quad * 8 + 4);
    ushort8_t f = {f2bf(a.x), f2bf(a.y), f2bf(a.z), f2bf(a.w),
                   f2bf(c.x), f2bf(c.y), f2bf(c.z), f2bf(c.w)};
    *(ushort8_t*)(dst + (((w16 * 4 + i) * 16 + l15) * 4 + quad) * 8) = f;
  }
}

// ---------------------------------------------------------------------------
// Cast V -> Vtf (transposed, fragment-ordered bf16). grid (NB, 32), 256 thr.
// Stage 1 = verified pass2 Wt staging (xor-swizzled); stage 2 reads the
// verified aw-fragment pattern and stores it linearly -> coalesced writes.
// ---------------------------------------------------------------------------
__global__ __launch_bounds__(256, 2) void cast_vt(
    const float* __restrict__ V, unsigned short* __restrict__ Vtf)
{
  const int b = blockIdx.x, t = blockIdx.y;
  const int tid = threadIdx.x;
  __shared__ unsigned short Wt[128][72];

  const float* Vb = V + ((size_t)b * SS + t * 64) * DQ;
  const int vk2 = (tid >> 5) * 2, sc4 = (tid & 31) * 4;
#pragma unroll
  for (int r = 0; r < 4; ++r) {
    int k2 = vk2 + r * 16;
    float4 a  = *(const float4*)(Vb + (size_t)k2 * DQ + sc4);
    float4 c2 = *(const float4*)(Vb + (size_t)(k2 + 1) * DQ + sc4);
    float fa[4] = {a.x, a.y, a.z, a.w};
    float fb[4] = {c2.x, c2.y, c2.z, c2.w};
#pragma unroll
    for (int i = 0; i < 4; ++i) {
      int d  = sc4 + i;
      int kk = k2 ^ ((((unsigned)d >> 2) & 7) << 3);
      *(ushort2*)&Wt[d][kk] = make_ushort2(f2bf(fa[i]), f2bf(fb[i]));
    }
  }
  bar_lds();

  unsigned short* dst = Vtf + ((size_t)b * 32 + t) * 8192;
#pragma unroll
  for (int it = 0; it < 4; ++it) {
    int idx = tid + 256 * it;            // = ((j*2+c)*16+l15)*4+quad
    int j = idx >> 7, c = (idx >> 6) & 1, l15 = (idx >> 2) & 15, quad = idx & 3;
    int d  = 16 * j + l15;
    int kk = (32 * c + quad * 8) ^ ((((unsigned)d >> 2) & 7) << 3);
    *(ushort8_t*)(dst + (size_t)idx * 8) = *(const ushort8_t*)&Wt[d][kk];
  }
}

// ---------------------------------------------------------------------------
// Pass 1 (fragment path): colsum[b][k] += sum_q exp(masked_score).
// grid (32 kt, NB, 4 qc), 256 thr, 4 blocks/CU. ZERO staging, ZERO loop
// barriers, ZERO f2bf: all operands pre-converted fragment-ordered bf16
// (L2/L3-resident). Per iter: 4 Q-frag loads + 1 mask word + 16 MFMA + 16 exp.
// ---------------------------------------------------------------------------
__global__ __launch_bounds__(256, 4) void pass1_frag(
    const unsigned short* __restrict__ Qf, const unsigned short* __restrict__ Kf,
    const u64* __restrict__ Mb, float* __restrict__ O)
{
  const int kt = blockIdx.x, b = blockIdx.y, qc = blockIdx.z;
  const int tid = threadIdx.x;
  const int w = tid >> 6, lane = tid & 63, l15 = lane & 15, quad = lane >> 4;

  __shared__ float red[4][64];

  const size_t lq = (size_t)(l15 * 4 + quad) * 8;
  const unsigned short* kfb = Kf + ((size_t)b * 32 + kt) * 8192 + lq;
  const u64* Mbb = Mb + (size_t)b * SS * 32 + kt;

  float colacc[16];
#pragma unroll
  for (int i = 0; i < 16; ++i) colacc[i] = 0.f;

  // prologue: prefetch q-tile 0 frags + mask word
  FragU qn[4];
  u64 mwn;
  {
    const int t = qc * 8;
    const unsigned short* qfb = Qf + ((size_t)(b * 32 + t) * 4 + w) * 2048 + lq;
#pragma unroll
    for (int i = 0; i < 4; ++i) qn[i].u = *(const ushort8_t*)(qfb + i * 512);
    mwn = Mbb[(size_t)(t * 64 + 16 * w + l15) * 32];
  }

  for (int qi = 0; qi < 8; ++qi) {
    FragU qf4[4] = {qn[0], qn[1], qn[2], qn[3]};
    u64 mw = mwn;
    if (qi < 7) {
      const int t = qc * 8 + qi + 1;
      const unsigned short* qfb = Qf + ((size_t)(b * 32 + t) * 4 + w) * 2048 + lq;
#pragma unroll
      for (int i = 0; i < 4; ++i) qn[i].u = *(const ushort8_t*)(qfb + i * 512);
      mwn = Mbb[(size_t)(t * 64 + 16 * w + l15) * 32];
    }

    floatx4 acc[4];
#pragma unroll
    for (int s = 0; s < 4; ++s) acc[s] = (floatx4){0.f, 0.f, 0.f, 0.f};
#pragma unroll
    for (int i = 0; i < 4; ++i) {
      bf16x8 bq = qf4[i].b;
#pragma unroll
      for (int s = 0; s < 4; ++s) {
        bf16x8 ak = ld_frag(kfb + (s * 4 + i) * 512);
        acc[s] = mfma16(ak, bq, acc[s]);
      }
    }
    // epilogue: C row = k_local = 16s+quad*4+r, col = q
#pragma unroll
    for (int s = 0; s < 4; ++s) {
#pragma unroll
      for (int r = 0; r < 4; ++r) {
        int m = (int)(mw >> (16 * s + quad * 4 + r)) & 1;
        float sv = m ? 1e-9f : acc[s][r] * SCALE;
        colacc[s * 4 + r] += __expf(sv);
      }
    }
  }

  // reduce over the 16 q-lanes (l15 dimension)
#pragma unroll
  for (int t = 0; t < 16; ++t) {
    colacc[t] += __shfl_xor(colacc[t], 1, 64);
    colacc[t] += __shfl_xor(colacc[t], 2, 64);
    colacc[t] += __shfl_xor(colacc[t], 4, 64);
    colacc[t] += __shfl_xor(colacc[t], 8, 64);
  }
  if (l15 == 0) {
#pragma unroll
    for (int s = 0; s < 4; ++s)
#pragma unroll
      for (int r = 0; r < 4; ++r)
        red[w][16 * s + quad * 4 + r] = colacc[s * 4 + r];
  }
  bar_lds();
  if (tid < 64) {
    float s = red[0][tid] + red[1][tid] + red[2][tid] + red[3][tid];
    atomicAdd(O + (size_t)b * SS * DQ + 16 * DQ + kt * 64 + tid, s);
  }
}

// ---------------------------------------------------------------------------
// Combine: inv = 1/colsum; write replicated strips. grid (NB, 8), 256 thr.
// ---------------------------------------------------------------------------
__global__ void combine_linv(float* __restrict__ O) {
  const int b  = blockIdx.x;
  const int jb = blockIdx.y * 4;
  float* Ob = O + (size_t)b * SS * DQ;
#pragma unroll
  for (int it = 0; it < 8; ++it) {
    int k = threadIdx.x + 256 * it;
    float inv = 1.0f / Ob[16 * DQ + k];
#pragma unroll
    for (int j = 0; j < 4; ++j)
      Ob[(size_t)(64 * (jb + j)) * DQ + k] = inv;
  }
}

// ---------------------------------------------------------------------------
// Pass 2 (fragment path): O[q][d] = sum_k exp(score)*Linv[k]*V[k][d].
// grid (32, NB), 256 thr. K/V/Q fragments direct from L2-resident
// fragment-ordered arrays; only wave-private Es transpose + Li in LDS;
// NO per-iteration barriers. Per k-tile: 33 coalesced loads, 32 MFMA, 16 exp.
// ---------------------------------------------------------------------------
__global__ __launch_bounds__(256, 2) void pass2_frag(
    const unsigned short* __restrict__ Qf, const unsigned short* __restrict__ Kf,
    const unsigned short* __restrict__ Vtf, const u64* __restrict__ Mb,
    float* __restrict__ O)
{
  const int b = blockIdx.y, q0 = blockIdx.x * 64;
  const int tid = threadIdx.x;
  const int w = tid >> 6, lane = tid & 63, l15 = lane & 15, quad = lane >> 4;

  __shared__ unsigned short Es[64][72];   // [q][k], wave-private rows
  __shared__ float Li[SS];

  // preload replicated Linv strip (before any O write)
  {
    const float* src = O + ((size_t)b * SS + q0) * DQ;
#pragma unroll
    for (int r = 0; r < 2; ++r) {
      int idx = (tid + r * 256) * 4;
      *(float4*)&Li[idx] = *(const float4*)(src + idx);
    }
  }

  const size_t lq = (size_t)(l15 * 4 + quad) * 8;
  // Q fragments resident (this lane's q row)
  FragU qf4[4];
  {
    const unsigned short* qfb =
        Qf + ((size_t)(b * 32 + (q0 >> 6)) * 4 + w) * 2048 + lq;
#pragma unroll
    for (int i = 0; i < 4; ++i) qf4[i].u = *(const ushort8_t*)(qfb + i * 512);
  }
  const u64* brow = Mb + (size_t)(b * SS + q0 + 16 * w + l15) * 32;

  floatx4 accO[8];
#pragma unroll
  for (int j = 0; j < 8; ++j) accO[j] = (floatx4){0.f, 0.f, 0.f, 0.f};

  bar_lds();   // Li ready (the only block barrier)

  u64 mwn = brow[0];
  for (int kt = 0; kt < 32; ++kt) {
    u64 mw = mwn;
    if (kt < 31) mwn = brow[kt + 1];
    const unsigned short* kfb = Kf + ((size_t)b * 32 + kt) * 8192 + lq;
    const unsigned short* vfb = Vtf + ((size_t)b * 32 + kt) * 8192 + lq;
    const int k0 = kt * 64;

    // QK: C row = k_local = 16j+quad*4+r, col = q = q0+16w+l15
    floatx4 acc[4];
#pragma unroll
    for (int j = 0; j < 4; ++j) acc[j] = (floatx4){0.f, 0.f, 0.f, 0.f};
#pragma unroll
    for (int i = 0; i < 4; ++i) {
      bf16x8 bq = qf4[i].b;
#pragma unroll
      for (int j = 0; j < 4; ++j) {
        bf16x8 ak = ld_frag(kfb + (j * 4 + i) * 512);
        acc[j] = mfma16(ak, bq, acc[j]);
      }
    }
    // epilogue: mask+exp, fold Linv, write Es (own wave's rows only)
#pragma unroll
    for (int j = 0; j < 4; ++j) {
      float4 liv = *(const float4*)&Li[k0 + 16 * j + quad * 4];
      float lv[4] = {liv.x, liv.y, liv.z, liv.w};
      unsigned short es[4];
#pragma unroll
      for (int r = 0; r < 4; ++r) {
        int m = (int)(mw >> (16 * j + quad * 4 + r)) & 1;
        float sv = m ? 1e-9f : acc[j][r] * SCALE;
        es[r] = f2bf(__expf(sv) * lv[r]);
      }
      *(ushort4*)&Es[16 * w + l15][16 * j + quad * 4] =
          make_ushort4(es[0], es[1], es[2], es[3]);
    }
    // PV (no barrier: Es rows written & read by the same wave; lgkm ordering)
#pragma unroll
    for (int c = 0; c < 2; ++c) {
      bf16x8 be = ld_frag(&Es[16 * w + l15][32 * c + quad * 8]);
#pragma unroll
      for (int j = 0; j < 8; ++j) {
        bf16x8 aw = ld_frag(vfb + (j * 2 + c) * 512);
        accO[j] = mfma16(aw, be, accO[j]);
      }
    }
  }

  // write O: C row = d = 16j+quad*4+r, col = q = q0+16w+l15
#pragma unroll
  for (int j = 0; j < 8; ++j) {
    float* op = O + ((size_t)b * SS + q0 + 16 * w + l15) * DQ + 16 * j + quad * 4;
    *(float4*)op = make_float4(accO[j][0], accO[j][1], accO[j][2], accO[j][3]);
  }
}

// ---------------------------------------------------------------------------
// FALLBACK path (no workspace): raw-mask pass1 + recompute pass2, verified.
// ---------------------------------------------------------------------------
__global__ __launch_bounds__(256, 4) void pass1_colsum(
    const float* __restrict__ Q, const float* __restrict__ K,
    const int* __restrict__ M, float* __restrict__ O)
{
  const int k0  = blockIdx.x * 64;
  const int b   = blockIdx.y;
  const int qc  = blockIdx.z;
  const int tid = threadIdx.x;
  const int w = tid >> 6, lane = tid & 63, l15 = lane & 15, quad = lane >> 4;

  __shared__ unsigned short Kbf[64][136];
  __shared__ unsigned short Qbf[64][136];
  __shared__ float red[4][64];

  const float* Qb = Q + (size_t)b * SS * DQ;
  const float* Kb = K + (size_t)b * SS * DQ;
  const int*   Mb = M + (size_t)b * SS * SS;

  const int srow = tid >> 5;
  const int sc4  = (tid & 31) * 4;

#pragma unroll
  for (int r = 0; r < 8; ++r) {
    int row = srow + r * 8;
    float4 v = *(const float4*)(Kb + (size_t)(k0 + row) * DQ + sc4);
    *(ushort4*)&Kbf[row][sc4] = make_ushort4(f2bf(v.x), f2bf(v.y), f2bf(v.z), f2bf(v.w));
  }

  const int qlane = 16 * w + l15;

  float4 qreg[8];
  int4 mv_nxt[4];
  {
    const int q0 = qc * 512;
#pragma unroll
    for (int r = 0; r < 8; ++r)
      qreg[r] = *(const float4*)(Qb + (size_t)(q0 + srow + r * 8) * DQ + sc4);
#pragma unroll
    for (int i = 0; i < 4; ++i)
      mv_nxt[i] = *(const int4*)(Mb + (size_t)(q0 + qlane) * SS + k0 + 16 * i + quad * 4);
  }

  float colacc[16];
#pragma unroll
  for (int t = 0; t < 16; ++t) colacc[t] = 0.f;

  for (int qi = 0; qi < 8; ++qi) {
    bar_lds();
    int4 mv[4] = {mv_nxt[0], mv_nxt[1], mv_nxt[2], mv_nxt[3]};
#pragma unroll
    for (int r = 0; r < 8; ++r) {
      float4 v = qreg[r];
      *(ushort4*)&Qbf[srow + r * 8][sc4] =
          make_ushort4(f2bf(v.x), f2bf(v.y), f2bf(v.z), f2bf(v.w));
    }
    bar_lds();
    if (qi < 7) {
      const int qn = qc * 512 + (qi + 1) * 64;
#pragma unroll
      for (int r = 0; r < 8; ++r)
        qreg[r] = *(const float4*)(Qb + (size_t)(qn + srow + r * 8) * DQ + sc4);
#pragma unroll
      for (int i = 0; i < 4; ++i)
        mv_nxt[i] = *(const int4*)(Mb + (size_t)(qn + qlane) * SS + k0 + 16 * i + quad * 4);
    }

    floatx4 acc[4];
#pragma unroll
    for (int i = 0; i < 4; ++i) acc[i] = (floatx4){0.f, 0.f, 0.f, 0.f};
#pragma unroll
    for (int d0 = 0; d0 < DQ; d0 += 32) {
      bf16x8 bq = ld_frag(&Qbf[qlane][d0 + quad * 8]);
#pragma unroll
      for (int i = 0; i < 4; ++i) {
        bf16x8 ak = ld_frag(&Kbf[16 * i + l15][d0 + quad * 8]);
        acc[i] = mfma16(ak, bq, acc[i]);
      }
    }
#pragma unroll
    for (int i = 0; i < 4; ++i) {
      int mm[4] = {mv[i].x, mv[i].y, mv[i].z, mv[i].w};
#pragma unroll
      for (int r = 0; r < 4; ++r) {
        float s = mm[r] ? 1e-9f : acc[i][r] * SCALE;
        colacc[i * 4 + r] += __expf(s);
      }
    }
  }

#pragma unroll
  for (int t = 0; t < 16; ++t) {
    colacc[t] += __shfl_xor(colacc[t], 1, 64);
    colacc[t] += __shfl_xor(colacc[t], 2, 64);
    colacc[t] += __shfl_xor(colacc[t], 4, 64);
    colacc[t] += __shfl_xor(colacc[t], 8, 64);
  }
  if (l15 == 0) {
#pragma unroll
    for (int i = 0; i < 4; ++i)
#pragma unroll
      for (int r = 0; r < 4; ++r)
        red[w][16 * i + quad * 4 + r] = colacc[i * 4 + r];
  }
  bar_lds();
  if (tid < 64) {
    float s = red[0][tid] + red[1][tid] + red[2][tid] + red[3][tid];
    atomicAdd(O + (size_t)b * SS * DQ + 16 * DQ + k0 + tid, s);
  }
}

__global__ __launch_bounds__(256, 2) void pass2_out(
    const float* __restrict__ Q, const float* __restrict__ K,
    const float* __restrict__ V, const int* __restrict__ M,
    float* __restrict__ O)
{
  const int b = blockIdx.y, q0 = blockIdx.x * 64;
  const int tid = threadIdx.x;
  const int w = tid >> 6, lane = tid & 63, l15 = lane & 15, quad = lane >> 4;

  __shared__ unsigned short Kbf[64][136];
  __shared__ unsigned short Es[64][72];
  __shared__ unsigned short Wt[128][72];
  __shared__ float Li[SS];

  const float* Qb = Q + (size_t)b * SS * DQ;
  const float* Kb = K + (size_t)b * SS * DQ;
  const float* Vb = V + (size_t)b * SS * DQ;
  const int*   Mb = M + (size_t)b * SS * SS;

  const int srow = tid >> 5;
  const int sc4  = (tid & 31) * 4;

  {
    const float* src = O + ((size_t)b * SS + q0) * DQ;
#pragma unroll
    for (int r = 0; r < 2; ++r) {
      int idx = (tid + r * 256) * 4;
      *(float4*)&Li[idx] = *(const float4*)(src + idx);
    }
  }
  FragU qf[4];
  {
    const float* qrow = Qb + (size_t)(q0 + 16 * w + l15) * DQ;
#pragma unroll
    for (int i = 0; i < 4; ++i) {
      float4 a = *(const float4*)(qrow + 32 * i + quad * 8);
      float4 c = *(const float4*)(qrow + 32 * i + quad * 8 + 4);
      qf[i].u = (ushort8_t){f2bf(a.x), f2bf(a.y), f2bf(a.z), f2bf(a.w),
                            f2bf(c.x), f2bf(c.y), f2bf(c.z), f2bf(c.w)};
    }
  }

  floatx4 accO[8];
#pragma unroll
  for (int j = 0; j < 8; ++j) accO[j] = (floatx4){0.f, 0.f, 0.f, 0.f};

  const int* mrow = Mb + (size_t)(q0 + 16 * w + l15) * SS;

  float4 kreg[8], vreg[8];
  int4 mv_nxt[4];
  const int vk2 = (tid >> 5) * 2;
  {
#pragma unroll
    for (int r = 0; r < 8; ++r)
      kreg[r] = *(const float4*)(Kb + (size_t)(srow + r * 8) * DQ + sc4);
#pragma unroll
    for (int r = 0; r < 4; ++r) {
      int k2 = vk2 + r * 16;
      vreg[2 * r]     = *(const float4*)(Vb + (size_t)(k2)     * DQ + sc4);
      vreg[2 * r + 1] = *(const float4*)(Vb + (size_t)(k2 + 1) * DQ + sc4);
    }
#pragma unroll
    for (int j = 0; j < 4; ++j)
      mv_nxt[j] = *(const int4*)(mrow + 16 * j + quad * 4);
  }

  for (int k0 = 0; k0 < SS; k0 += 64) {
    bar_lds();
    int4 mv[4] = {mv_nxt[0], mv_nxt[1], mv_nxt[2], mv_nxt[3]};

#pragma unroll
    for (int r = 0; r < 8; ++r) {
      float4 v = kreg[r];
      *(ushort4*)&Kbf[srow + r * 8][sc4] =
          make_ushort4(f2bf(v.x), f2bf(v.y), f2bf(v.z), f2bf(v.w));
    }
#pragma unroll
    for (int r = 0; r < 4; ++r) {
      int k2 = vk2 + r * 16;
      float fa[4] = {vreg[2*r].x, vreg[2*r].y, vreg[2*r].z, vreg[2*r].w};
      float fb[4] = {vreg[2*r+1].x, vreg[2*r+1].y, vreg[2*r+1].z, vreg[2*r+1].w};
#pragma unroll
      for (int i = 0; i < 4; ++i) {
        int d  = sc4 + i;
        int kk = k2 ^ ((((unsigned)d >> 2) & 7) << 3);
        *(ushort2*)&Wt[d][kk] = make_ushort2(f2bf(fa[i]), f2bf(fb[i]));
      }
    }
    bar_lds();

    if (k0 + 64 < SS) {
      const int kn = k0 + 64;
#pragma unroll
      for (int r = 0; r < 8; ++r)
        kreg[r] = *(const float4*)(Kb + (size_t)(kn + srow + r * 8) * DQ + sc4);
#pragma unroll
      for (int r = 0; r < 4; ++r) {
        int k2 = vk2 + r * 16;
        vreg[2 * r]     = *(const float4*)(Vb + (size_t)(kn + k2)     * DQ + sc4);
        vreg[2 * r + 1] = *(const float4*)(Vb + (size_t)(kn + k2 + 1) * DQ + sc4);
      }
#pragma unroll
      for (int j = 0; j < 4; ++j)
        mv_nxt[j] = *(const int4*)(mrow + kn + 16 * j + quad * 4);
    }

    floatx4 acc[4];
#pragma unroll
    for (int j = 0; j < 4; ++j) acc[j] = (floatx4){0.f, 0.f, 0.f, 0.f};
#pragma unroll
    for (int i = 0; i < 4; ++i) {
      bf16x8 bq = qf[i].b;
#pragma unroll
      for (int j = 0; j < 4; ++j) {
        bf16x8 ak = ld_frag(&Kbf[16 * j + l15][32 * i + quad * 8]);
        acc[j] = mfma16(ak, bq, acc[j]);
      }
    }
#pragma unroll
    for (int j = 0; j < 4; ++j) {
      float4 liv = *(const float4*)&Li[k0 + 16 * j + quad * 4];
      float lv[4] = {liv.x, liv.y, liv.z, liv.w};
      int mm[4] = {mv[j].x, mv[j].y, mv[j].z, mv[j].w};
      unsigned short es[4];
#pragma unroll
      for (int r = 0; r < 4; ++r) {
        float s = mm[r] ? 1e-9f : acc[j][r] * SCALE;
        es[r] = f2bf(__expf(s) * lv[r]);
      }
      *(ushort4*)&Es[16 * w + l15][16 * j + quad * 4] =
          make_ushort4(es[0], es[1], es[2], es[3]);
    }
#pragma unroll
    for (int c = 0; c < 2; ++c) {
      bf16x8 be = ld_frag(&Es[16 * w + l15][32 * c + quad * 8]);
#pragma unroll
      for (int j = 0; j < 8; ++j) {
        int d  = 16 * j + l15;
        int kk = (32 * c + quad * 8) ^ ((((unsigned)d >> 2) & 7) << 3);
        bf16x8 aw = ld_frag(&Wt[d][kk]);
        accO[j] = mfma16(aw, be, accO[j]);
      }
    }
  }

#pragma unroll
  for (int j = 0; j < 8; ++j) {
    float* op = O + ((size_t)b * SS + q0 + 16 * w + l15) * DQ + 16 * j + quad * 4;
    *(float4*)op = make_float4(accO[j][0], accO[j][1], accO[j][2], accO[j][3]);
  }
}

// ---------------------------------------------------------------------------
extern "C" void kernel_launch(void* const* d_in, const int* in_sizes, int n_in,
                              void* d_out, int out_size, void* d_ws, size_t ws_size,
                              hipStream_t stream) {
  const float* Q = (const float*)d_in[0];
  const float* K = (const float*)d_in[1];
  const float* V = (const float*)d_in[2];
  const int*   M = (const int*)d_in[3];
  float* O = (float*)d_out;

  const size_t msz = (size_t)NB * SS * 32 * sizeof(u64);             // 8 MiB
  const size_t fsz = (size_t)NB * SS * DQ * sizeof(unsigned short);  // 8 MiB
  const size_t need = msz + 3 * fsz;                                 // 32 MiB

  zero_accum<<<dim3(NB), 256, 0, stream>>>(O);
  if (d_ws != nullptr && ws_size >= need) {
    u64* Mbp = (u64*)d_ws;
    unsigned short* Qf  = (unsigned short*)((char*)d_ws + msz);
    unsigned short* Kf  = (unsigned short*)((char*)d_ws + msz + fsz);
    unsigned short* Vtf = (unsigned short*)((char*)d_ws + msz + 2 * fsz);
    compress_mask<<<dim3(NB, 512), 256, 0, stream>>>(M, Mbp);
    cast_qk<<<dim3(NB, 32, 2), 256, 0, stream>>>(Q, K, Qf, Kf);
    cast_vt<<<dim3(NB, 32), 256, 0, stream>>>(V, Vtf);
    pass1_frag<<<dim3(32, NB, 4), 256, 0, stream>>>(Qf, Kf, Mbp, O);
    combine_linv<<<dim3(NB, 8), 256, 0, stream>>>(O);
    pass2_frag<<<dim3(32, NB), 256, 0, stream>>>(Qf, Kf, Vtf, Mbp, O);
  } else {
    pass1_colsum<<<dim3(32, NB, 4), 256, 0, stream>>>(Q, K, M, O);
    combine_linv<<<dim3(NB, 8), 256, 0, stream>>>(O);
    pass2_out<<<dim3(32, NB), 256, 0, stream>>>(Q, K, V, M, O);
  }
}

// Round 8
// 643.717 us; speedup vs baseline: 1.1491x; 1.1491x over previous
//
#include <hip/hip_runtime.h>
#include <math.h>

#define NB 16
#define SS 2048
#define DQ 128
#define SCALE 0.08838834764831845f  // 1/sqrt(128)

typedef __bf16 bf16x8 __attribute__((ext_vector_type(8)));
typedef unsigned short ushort8_t __attribute__((ext_vector_type(8)));
typedef float floatx4 __attribute__((ext_vector_type(4)));
typedef unsigned long long u64;

// fp32 -> bf16 round-to-nearest-even (finite randn inputs; no NaN path)
__device__ __forceinline__ unsigned short f2bf(float x) {
  unsigned int u = __float_as_uint(x);
  u += 0x7fffu + ((u >> 16) & 1u);
  return (unsigned short)(u >> 16);
}
union FragU { ushort8_t u; bf16x8 b; };
__device__ __forceinline__ bf16x8 ld_frag(const unsigned short* p) {
  FragU t; t.u = *(const ushort8_t*)p; return t.b;
}
__device__ __forceinline__ floatx4 mfma16(bf16x8 a, bf16x8 b, floatx4 c) {
  return __builtin_amdgcn_mfma_f32_16x16x32_bf16(a, b, c, 0, 0, 0);
}

// LDS-only barrier: waits DS ops, leaves global loads (vmcnt) IN FLIGHT.
__device__ __forceinline__ void bar_lds() {
  asm volatile("s_waitcnt lgkmcnt(0)\n\ts_barrier" ::: "memory");
}

// d_out scratch per batch b: rows 16..31 = colsum accumulator.
// d_ws layout: [0,8Mi) Mbits u64; [8,16Mi) Qf; [16,24Mi) Kf; [24,32Mi) Vtf;
// [32,33Mi) Lf[b][k] f32 = 1/colsum; [33Mi, 33Mi+64Mi) P: 4 partial-O slabs.
// Fragment-ordered bf16:
//  Qf[b][t=q/64][w=(q%64)/16][i=d/32][l15=q%16][quad=(d%32)/8][e=d%8]
//  Kf[b][t=k/64][s=(k%64)/16][i=d/32][l15=k%16][quad][e]      (A-frag order)
//  Vtf[b][t=k/64][j=d/16][c=(k%64)/32][l15=d%16][quad=(k%32)/8][e=k%8]

// ---------------------------------------------------------------------------
__global__ void zero_accum(float* __restrict__ O) {
  float* p = O + (size_t)blockIdx.x * SS * DQ + 16 * DQ;
#pragma unroll
  for (int i = 0; i < 8; ++i) p[threadIdx.x + 256 * i] = 0.f;
}

// ---------------------------------------------------------------------------
// Compress mask: 268 MB int32 -> 8 MB bit-words (verified round 6).
// ---------------------------------------------------------------------------
__global__ __launch_bounds__(256) void compress_mask(
    const int* __restrict__ M, u64* __restrict__ Mb)
{
  const int b = blockIdx.x;
  const int q = blockIdx.y * 4 + (threadIdx.x >> 6);
  const int lane = threadIdx.x & 63;

  const int* row = M + ((size_t)b * SS + q) * SS;
  int v[32];
#pragma unroll
  for (int kt = 0; kt < 32; ++kt) v[kt] = row[kt * 64 + lane];

  u64 w = 0;
#pragma unroll
  for (int kt = 0; kt < 32; ++kt) {
    u64 bal = __ballot(v[kt] != 0);
    if (lane == kt) w = bal;
  }
  u64* orow = Mb + ((size_t)b * SS + q) * 32;
  if (lane < 32) orow[lane] = w;
}

// ---------------------------------------------------------------------------
// Cast Q and K (z=0: Q->Qf, z=1: K->Kf) into fragment-ordered bf16.
// ---------------------------------------------------------------------------
__global__ __launch_bounds__(256) void cast_qk(
    const float* __restrict__ Q, const float* __restrict__ K,
    unsigned short* __restrict__ Qf, unsigned short* __restrict__ Kf)
{
  const int b = blockIdx.x, t = blockIdx.y;
  const float* src = (blockIdx.z ? K : Q) + ((size_t)b * SS + t * 64) * DQ;
  unsigned short* dst = (blockIdx.z ? Kf : Qf) + ((size_t)b * 32 + t) * 8192;
  const int tid = threadIdx.x;
  const int w16 = tid >> 6, l15 = (tid >> 2) & 15, quad = tid & 3;
  const float* row = src + (size_t)(16 * w16 + l15) * DQ;
#pragma unroll
  for (int i = 0; i < 4; ++i) {
    float4 a = *(const float4*)(row + 32 * i + quad * 8);
    float4 c = *(const float4*)(row + 32 * i + quad * 8 + 4);
    ushort8_t f = {f2bf(a.x), f2bf(a.y), f2bf(a.z), f2bf(a.w),
                   f2bf(c.x), f2bf(c.y), f2bf(c.z), f2bf(c.w)};
    *(ushort8_t*)(dst + (((w16 * 4 + i) * 16 + l15) * 4 + quad) * 8) = f;
  }
}

// ---------------------------------------------------------------------------
// Cast V -> Vtf (transposed, fragment-ordered bf16). grid (NB, 32), 256 thr.
// ---------------------------------------------------------------------------
__global__ __launch_bounds__(256, 2) void cast_vt(
    const float* __restrict__ V, unsigned short* __restrict__ Vtf)
{
  const int b = blockIdx.x, t = blockIdx.y;
  const int tid = threadIdx.x;
  __shared__ unsigned short Wt[128][72];

  const float* Vb = V + ((size_t)b * SS + t * 64) * DQ;
  const int vk2 = (tid >> 5) * 2, sc4 = (tid & 31) * 4;
#pragma unroll
  for (int r = 0; r < 4; ++r) {
    int k2 = vk2 + r * 16;
    float4 a  = *(const float4*)(Vb + (size_t)k2 * DQ + sc4);
    float4 c2 = *(const float4*)(Vb + (size_t)(k2 + 1) * DQ + sc4);
    float fa[4] = {a.x, a.y, a.z, a.w};
    float fb[4] = {c2.x, c2.y, c2.z, c2.w};
#pragma unroll
    for (int i = 0; i < 4; ++i) {
      int d  = sc4 + i;
      int kk = k2 ^ ((((unsigned)d >> 2) & 7) << 3);
      *(ushort2*)&Wt[d][kk] = make_ushort2(f2bf(fa[i]), f2bf(fb[i]));
    }
  }
  bar_lds();

  unsigned short* dst = Vtf + ((size_t)b * 32 + t) * 8192;
#pragma unroll
  for (int it = 0; it < 4; ++it) {
    int idx = tid + 256 * it;            // = ((j*2+c)*16+l15)*4+quad
    int j = idx >> 7, c = (idx >> 6) & 1, l15 = (idx >> 2) & 15, quad = idx & 3;
    int d  = 16 * j + l15;
    int kk = (32 * c + quad * 8) ^ ((((unsigned)d >> 2) & 7) << 3);
    *(ushort8_t*)(dst + (size_t)idx * 8) = *(const ushort8_t*)&Wt[d][kk];
  }
}

// ---------------------------------------------------------------------------
// Pass 1 (fragment path, round-7 verbatim): colsum += sum_q exp(score).
// grid (32 kt, NB, 4 qc), 256 thr; ~1KB LDS -> high occupancy available.
// ---------------------------------------------------------------------------
__global__ __launch_bounds__(256, 4) void pass1_frag(
    const unsigned short* __restrict__ Qf, const unsigned short* __restrict__ Kf,
    const u64* __restrict__ Mb, float* __restrict__ O)
{
  const int kt = blockIdx.x, b = blockIdx.y, qc = blockIdx.z;
  const int tid = threadIdx.x;
  const int w = tid >> 6, lane = tid & 63, l15 = lane & 15, quad = lane >> 4;

  __shared__ float red[4][64];

  const size_t lq = (size_t)(l15 * 4 + quad) * 8;
  const unsigned short* kfb = Kf + ((size_t)b * 32 + kt) * 8192 + lq;
  const u64* Mbb = Mb + (size_t)b * SS * 32 + kt;

  float colacc[16];
#pragma unroll
  for (int i = 0; i < 16; ++i) colacc[i] = 0.f;

  FragU qn[4];
  u64 mwn;
  {
    const int t = qc * 8;
    const unsigned short* qfb = Qf + ((size_t)(b * 32 + t) * 4 + w) * 2048 + lq;
#pragma unroll
    for (int i = 0; i < 4; ++i) qn[i].u = *(const ushort8_t*)(qfb + i * 512);
    mwn = Mbb[(size_t)(t * 64 + 16 * w + l15) * 32];
  }

  for (int qi = 0; qi < 8; ++qi) {
    FragU qf4[4] = {qn[0], qn[1], qn[2], qn[3]};
    u64 mw = mwn;
    if (qi < 7) {
      const int t = qc * 8 + qi + 1;
      const unsigned short* qfb = Qf + ((size_t)(b * 32 + t) * 4 + w) * 2048 + lq;
#pragma unroll
      for (int i = 0; i < 4; ++i) qn[i].u = *(const ushort8_t*)(qfb + i * 512);
      mwn = Mbb[(size_t)(t * 64 + 16 * w + l15) * 32];
    }

    floatx4 acc[4];
#pragma unroll
    for (int s = 0; s < 4; ++s) acc[s] = (floatx4){0.f, 0.f, 0.f, 0.f};
#pragma unroll
    for (int i = 0; i < 4; ++i) {
      bf16x8 bq = qf4[i].b;
#pragma unroll
      for (int s = 0; s < 4; ++s) {
        bf16x8 ak = ld_frag(kfb + (s * 4 + i) * 512);
        acc[s] = mfma16(ak, bq, acc[s]);
      }
    }
#pragma unroll
    for (int s = 0; s < 4; ++s) {
#pragma unroll
      for (int r = 0; r < 4; ++r) {
        int m = (int)(mw >> (16 * s + quad * 4 + r)) & 1;
        float sv = m ? 1e-9f : acc[s][r] * SCALE;
        colacc[s * 4 + r] += __expf(sv);
      }
    }
  }

#pragma unroll
  for (int t = 0; t < 16; ++t) {
    colacc[t] += __shfl_xor(colacc[t], 1, 64);
    colacc[t] += __shfl_xor(colacc[t], 2, 64);
    colacc[t] += __shfl_xor(colacc[t], 4, 64);
    colacc[t] += __shfl_xor(colacc[t], 8, 64);
  }
  if (l15 == 0) {
#pragma unroll
    for (int s = 0; s < 4; ++s)
#pragma unroll
      for (int r = 0; r < 4; ++r)
        red[w][16 * s + quad * 4 + r] = colacc[s * 4 + r];
  }
  bar_lds();
  if (tid < 64) {
    float s = red[0][tid] + red[1][tid] + red[2][tid] + red[3][tid];
    atomicAdd(O + (size_t)b * SS * DQ + 16 * DQ + kt * 64 + tid, s);
  }
}

// ---------------------------------------------------------------------------
// Lf[b][k] = 1/colsum[b][k]. grid (NB), 256 thr. 128 KB.
// ---------------------------------------------------------------------------
__global__ void linv_make(const float* __restrict__ O, float* __restrict__ Lf) {
  const int b = blockIdx.x;
  const float* cs = O + (size_t)b * SS * DQ + 16 * DQ;
  float* lf = Lf + (size_t)b * SS;
#pragma unroll
  for (int i = 0; i < 8; ++i) {
    int k = threadIdx.x + 256 * i;
    lf[k] = 1.0f / cs[k];
  }
}

// ---------------------------------------------------------------------------
// Pass 2 (one-wave blocks, k-split 4): partial O = sum_{k in quarter}
// exp(score)*Linv[k]*V[k][d]. grid (128 qb, 4 kh, NB) = 8192 blocks of 64 thr
// -> 32 blocks/CU available (round-7's pass2_frag failed at 2 blocks/CU).
// Waves fully independent: Es is wave-private (compiler lgkmcnt orders the
// ds_write->ds_read, same as all verified variants); Linv from global Lf.
// ---------------------------------------------------------------------------
__global__ __launch_bounds__(64) void pass2_wave(
    const unsigned short* __restrict__ Qf, const unsigned short* __restrict__ Kf,
    const unsigned short* __restrict__ Vtf, const u64* __restrict__ Mb,
    const float* __restrict__ Lf, float* __restrict__ P)
{
  const int bx = blockIdx.x, kh = blockIdx.y, b = blockIdx.z;
  const int lane = threadIdx.x;
  const int l15 = lane & 15, quad = lane >> 4;

  __shared__ unsigned short Es[16][72];   // [q][k], wave-private

  const size_t lq = (size_t)(l15 * 4 + quad) * 8;
  // Q fragments resident (this lane's q row): q = bx*16 + l15
  FragU qf4[4];
  {
    const unsigned short* qfb =
        Qf + ((size_t)(b * 32 + (bx >> 2)) * 4 + (bx & 3)) * 2048 + lq;
#pragma unroll
    for (int i = 0; i < 4; ++i) qf4[i].u = *(const ushort8_t*)(qfb + i * 512);
  }
  const u64* brow = Mb + (size_t)(b * SS + bx * 16 + l15) * 32 + kh * 8;
  const float* lfb = Lf + (size_t)b * SS;

  floatx4 accO[8];
#pragma unroll
  for (int j = 0; j < 8; ++j) accO[j] = (floatx4){0.f, 0.f, 0.f, 0.f};

  for (int ki = 0; ki < 8; ++ki) {
    const int kt = kh * 8 + ki;
    const u64 mw = brow[ki];
    const unsigned short* kfb = Kf + ((size_t)b * 32 + kt) * 8192 + lq;
    const unsigned short* vfb = Vtf + ((size_t)b * 32 + kt) * 8192 + lq;
    const int k0 = kt * 64;

    // QK: C row = k_local = 16j+quad*4+r, col = q = bx*16+l15
    floatx4 acc[4];
#pragma unroll
    for (int j = 0; j < 4; ++j) acc[j] = (floatx4){0.f, 0.f, 0.f, 0.f};
#pragma unroll
    for (int i = 0; i < 4; ++i) {
      bf16x8 bq = qf4[i].b;
#pragma unroll
      for (int j = 0; j < 4; ++j) {
        bf16x8 ak = ld_frag(kfb + (j * 4 + i) * 512);
        acc[j] = mfma16(ak, bq, acc[j]);
      }
    }
    // epilogue: mask+exp, fold Linv, write Es
#pragma unroll
    for (int j = 0; j < 4; ++j) {
      float4 liv = *(const float4*)(lfb + k0 + 16 * j + quad * 4);
      float lv[4] = {liv.x, liv.y, liv.z, liv.w};
      unsigned short es[4];
#pragma unroll
      for (int r = 0; r < 4; ++r) {
        int m = (int)(mw >> (16 * j + quad * 4 + r)) & 1;
        float sv = m ? 1e-9f : acc[j][r] * SCALE;
        es[r] = f2bf(__expf(sv) * lv[r]);
      }
      *(ushort4*)&Es[l15][16 * j + quad * 4] =
          make_ushort4(es[0], es[1], es[2], es[3]);
    }
    // PV (compiler lgkmcnt orders Es write->read within the wave)
#pragma unroll
    for (int c = 0; c < 2; ++c) {
      bf16x8 be = ld_frag(&Es[l15][32 * c + quad * 8]);
#pragma unroll
      for (int j = 0; j < 8; ++j) {
        bf16x8 aw = ld_frag(vfb + (j * 2 + c) * 512);
        accO[j] = mfma16(aw, be, accO[j]);
      }
    }
  }

  // write partial: C row = d = 16j+quad*4+r, col = q = bx*16+l15
#pragma unroll
  for (int j = 0; j < 8; ++j) {
    float* op = P + (((size_t)(kh * NB + b) * SS) + bx * 16 + l15) * DQ
                  + 16 * j + quad * 4;
    *(float4*)op = make_float4(accO[j][0], accO[j][1], accO[j][2], accO[j][3]);
  }
}

// ---------------------------------------------------------------------------
// Sum the 4 k-quarter partials into O. grid (NB, 32), 256 thr. ~80 MB.
// ---------------------------------------------------------------------------
__global__ void combine_O(const float* __restrict__ P, float* __restrict__ O) {
  const size_t boff = (size_t)blockIdx.x * SS * DQ + (size_t)blockIdx.y * 8192;
  const size_t str = (size_t)NB * SS * DQ;
  const float* P0 = P + boff;
  float* Ob = O + boff;
#pragma unroll
  for (int it = 0; it < 8; ++it) {
    int i = (threadIdx.x + 256 * it) * 4;
    float4 a = *(const float4*)(P0 + i);
    float4 c = *(const float4*)(P0 + str + i);
    float4 d = *(const float4*)(P0 + 2 * str + i);
    float4 e = *(const float4*)(P0 + 3 * str + i);
    *(float4*)(Ob + i) = make_float4(a.x + c.x + d.x + e.x,
                                     a.y + c.y + d.y + e.y,
                                     a.z + c.z + d.z + e.z,
                                     a.w + c.w + d.w + e.w);
  }
}

// ---------------------------------------------------------------------------
// FALLBACK path (no workspace): raw-mask pass1 + recompute pass2, verified.
// ---------------------------------------------------------------------------
__global__ void combine_linv(float* __restrict__ O) {
  const int b  = blockIdx.x;
  const int jb = blockIdx.y * 4;
  float* Ob = O + (size_t)b * SS * DQ;
#pragma unroll
  for (int it = 0; it < 8; ++it) {
    int k = threadIdx.x + 256 * it;
    float inv = 1.0f / Ob[16 * DQ + k];
#pragma unroll
    for (int j = 0; j < 4; ++j)
      Ob[(size_t)(64 * (jb + j)) * DQ + k] = inv;
  }
}

__global__ __launch_bounds__(256, 4) void pass1_colsum(
    const float* __restrict__ Q, const float* __restrict__ K,
    const int* __restrict__ M, float* __restrict__ O)
{
  const int k0  = blockIdx.x * 64;
  const int b   = blockIdx.y;
  const int qc  = blockIdx.z;
  const int tid = threadIdx.x;
  const int w = tid >> 6, lane = tid & 63, l15 = lane & 15, quad = lane >> 4;

  __shared__ unsigned short Kbf[64][136];
  __shared__ unsigned short Qbf[64][136];
  __shared__ float red[4][64];

  const float* Qb = Q + (size_t)b * SS * DQ;
  const float* Kb = K + (size_t)b * SS * DQ;
  const int*   Mb = M + (size_t)b * SS * SS;

  const int srow = tid >> 5;
  const int sc4  = (tid & 31) * 4;

#pragma unroll
  for (int r = 0; r < 8; ++r) {
    int row = srow + r * 8;
    float4 v = *(const float4*)(Kb + (size_t)(k0 + row) * DQ + sc4);
    *(ushort4*)&Kbf[row][sc4] = make_ushort4(f2bf(v.x), f2bf(v.y), f2bf(v.z), f2bf(v.w));
  }

  const int qlane = 16 * w + l15;

  float4 qreg[8];
  int4 mv_nxt[4];
  {
    const int q0 = qc * 512;
#pragma unroll
    for (int r = 0; r < 8; ++r)
      qreg[r] = *(const float4*)(Qb + (size_t)(q0 + srow + r * 8) * DQ + sc4);
#pragma unroll
    for (int i = 0; i < 4; ++i)
      mv_nxt[i] = *(const int4*)(Mb + (size_t)(q0 + qlane) * SS + k0 + 16 * i + quad * 4);
  }

  float colacc[16];
#pragma unroll
  for (int t = 0; t < 16; ++t) colacc[t] = 0.f;

  for (int qi = 0; qi < 8; ++qi) {
    bar_lds();
    int4 mv[4] = {mv_nxt[0], mv_nxt[1], mv_nxt[2], mv_nxt[3]};
#pragma unroll
    for (int r = 0; r < 8; ++r) {
      float4 v = qreg[r];
      *(ushort4*)&Qbf[srow + r * 8][sc4] =
          make_ushort4(f2bf(v.x), f2bf(v.y), f2bf(v.z), f2bf(v.w));
    }
    bar_lds();
    if (qi < 7) {
      const int qn = qc * 512 + (qi + 1) * 64;
#pragma unroll
      for (int r = 0; r < 8; ++r)
        qreg[r] = *(const float4*)(Qb + (size_t)(qn + srow + r * 8) * DQ + sc4);
#pragma unroll
      for (int i = 0; i < 4; ++i)
        mv_nxt[i] = *(const int4*)(Mb + (size_t)(qn + qlane) * SS + k0 + 16 * i + quad * 4);
    }

    floatx4 acc[4];
#pragma unroll
    for (int i = 0; i < 4; ++i) acc[i] = (floatx4){0.f, 0.f, 0.f, 0.f};
#pragma unroll
    for (int d0 = 0; d0 < DQ; d0 += 32) {
      bf16x8 bq = ld_frag(&Qbf[qlane][d0 + quad * 8]);
#pragma unroll
      for (int i = 0; i < 4; ++i) {
        bf16x8 ak = ld_frag(&Kbf[16 * i + l15][d0 + quad * 8]);
        acc[i] = mfma16(ak, bq, acc[i]);
      }
    }
#pragma unroll
    for (int i = 0; i < 4; ++i) {
      int mm[4] = {mv[i].x, mv[i].y, mv[i].z, mv[i].w};
#pragma unroll
      for (int r = 0; r < 4; ++r) {
        float s = mm[r] ? 1e-9f : acc[i][r] * SCALE;
        colacc[i * 4 + r] += __expf(s);
      }
    }
  }

#pragma unroll
  for (int t = 0; t < 16; ++t) {
    colacc[t] += __shfl_xor(colacc[t], 1, 64);
    colacc[t] += __shfl_xor(colacc[t], 2, 64);
    colacc[t] += __shfl_xor(colacc[t], 4, 64);
    colacc[t] += __shfl_xor(colacc[t], 8, 64);
  }
  if (l15 == 0) {
#pragma unroll
    for (int i = 0; i < 4; ++i)
#pragma unroll
      for (int r = 0; r < 4; ++r)
        red[w][16 * i + quad * 4 + r] = colacc[i * 4 + r];
  }
  bar_lds();
  if (tid < 64) {
    float s = red[0][tid] + red[1][tid] + red[2][tid] + red[3][tid];
    atomicAdd(O + (size_t)b * SS * DQ + 16 * DQ + k0 + tid, s);
  }
}

__global__ __launch_bounds__(256, 2) void pass2_out(
    const float* __restrict__ Q, const float* __restrict__ K,
    const float* __restrict__ V, const int* __restrict__ M,
    float* __restrict__ O)
{
  const int b = blockIdx.y, q0 = blockIdx.x * 64;
  const int tid = threadIdx.x;
  const int w = tid >> 6, lane = tid & 63, l15 = lane & 15, quad = lane >> 4;

  __shared__ unsigned short Kbf[64][136];
  __shared__ unsigned short Es[64][72];
  __shared__ unsigned short Wt[128][72];
  __shared__ float Li[SS];

  const float* Qb = Q + (size_t)b * SS * DQ;
  const float* Kb = K + (size_t)b * SS * DQ;
  const float* Vb = V + (size_t)b * SS * DQ;
  const int*   Mb = M + (size_t)b * SS * SS;

  const int srow = tid >> 5;
  const int sc4  = (tid & 31) * 4;

  {
    const float* src = O + ((size_t)b * SS + q0) * DQ;
#pragma unroll
    for (int r = 0; r < 2; ++r) {
      int idx = (tid + r * 256) * 4;
      *(float4*)&Li[idx] = *(const float4*)(src + idx);
    }
  }
  FragU qf[4];
  {
    const float* qrow = Qb + (size_t)(q0 + 16 * w + l15) * DQ;
#pragma unroll
    for (int i = 0; i < 4; ++i) {
      float4 a = *(const float4*)(qrow + 32 * i + quad * 8);
      float4 c = *(const float4*)(qrow + 32 * i + quad * 8 + 4);
      qf[i].u = (ushort8_t){f2bf(a.x), f2bf(a.y), f2bf(a.z), f2bf(a.w),
                            f2bf(c.x), f2bf(c.y), f2bf(c.z), f2bf(c.w)};
    }
  }

  floatx4 accO[8];
#pragma unroll
  for (int j = 0; j < 8; ++j) accO[j] = (floatx4){0.f, 0.f, 0.f, 0.f};

  const int* mrow = Mb + (size_t)(q0 + 16 * w + l15) * SS;

  float4 kreg[8], vreg[8];
  int4 mv_nxt[4];
  const int vk2 = (tid >> 5) * 2;
  {
#pragma unroll
    for (int r = 0; r < 8; ++r)
      kreg[r] = *(const float4*)(Kb + (size_t)(srow + r * 8) * DQ + sc4);
#pragma unroll
    for (int r = 0; r < 4; ++r) {
      int k2 = vk2 + r * 16;
      vreg[2 * r]     = *(const float4*)(Vb + (size_t)(k2)     * DQ + sc4);
      vreg[2 * r + 1] = *(const float4*)(Vb + (size_t)(k2 + 1) * DQ + sc4);
    }
#pragma unroll
    for (int j = 0; j < 4; ++j)
      mv_nxt[j] = *(const int4*)(mrow + 16 * j + quad * 4);
  }

  for (int k0 = 0; k0 < SS; k0 += 64) {
    bar_lds();
    int4 mv[4] = {mv_nxt[0], mv_nxt[1], mv_nxt[2], mv_nxt[3]};

#pragma unroll
    for (int r = 0; r < 8; ++r) {
      float4 v = kreg[r];
      *(ushort4*)&Kbf[srow + r * 8][sc4] =
          make_ushort4(f2bf(v.x), f2bf(v.y), f2bf(v.z), f2bf(v.w));
    }
#pragma unroll
    for (int r = 0; r < 4; ++r) {
      int k2 = vk2 + r * 16;
      float fa[4] = {vreg[2*r].x, vreg[2*r].y, vreg[2*r].z, vreg[2*r].w};
      float fb[4] = {vreg[2*r+1].x, vreg[2*r+1].y, vreg[2*r+1].z, vreg[2*r+1].w};
#pragma unroll
      for (int i = 0; i < 4; ++i) {
        int d  = sc4 + i;
        int kk = k2 ^ ((((unsigned)d >> 2) & 7) << 3);
        *(ushort2*)&Wt[d][kk] = make_ushort2(f2bf(fa[i]), f2bf(fb[i]));
      }
    }
    bar_lds();

    if (k0 + 64 < SS) {
      const int kn = k0 + 64;
#pragma unroll
      for (int r = 0; r < 8; ++r)
        kreg[r] = *(const float4*)(Kb + (size_t)(kn + srow + r * 8) * DQ + sc4);
#pragma unroll
      for (int r = 0; r < 4; ++r) {
        int k2 = vk2 + r * 16;
        vreg[2 * r]     = *(const float4*)(Vb + (size_t)(kn + k2)     * DQ + sc4);
        vreg[2 * r + 1] = *(const float4*)(Vb + (size_t)(kn + k2 + 1) * DQ + sc4);
      }
#pragma unroll
      for (int j = 0; j < 4; ++j)
        mv_nxt[j] = *(const int4*)(mrow + kn + 16 * j + quad * 4);
    }

    floatx4 acc[4];
#pragma unroll
    for (int j = 0; j < 4; ++j) acc[j] = (floatx4){0.f, 0.f, 0.f, 0.f};
#pragma unroll
    for (int i = 0; i < 4; ++i) {
      bf16x8 bq = qf[i].b;
#pragma unroll
      for (int j = 0; j < 4; ++j) {
        bf16x8 ak = ld_frag(&Kbf[16 * j + l15][32 * i + quad * 8]);
        acc[j] = mfma16(ak, bq, acc[j]);
      }
    }
#pragma unroll
    for (int j = 0; j < 4; ++j) {
      float4 liv = *(const float4*)&Li[k0 + 16 * j + quad * 4];
      float lv[4] = {liv.x, liv.y, liv.z, liv.w};
      int mm[4] = {mv[j].x, mv[j].y, mv[j].z, mv[j].w};
      unsigned short es[4];
#pragma unroll
      for (int r = 0; r < 4; ++r) {
        float s = mm[r] ? 1e-9f : acc[j][r] * SCALE;
        es[r] = f2bf(__expf(s) * lv[r]);
      }
      *(ushort4*)&Es[16 * w + l15][16 * j + quad * 4] =
          make_ushort4(es[0], es[1], es[2], es[3]);
    }
#pragma unroll
    for (int c = 0; c < 2; ++c) {
      bf16x8 be = ld_frag(&Es[16 * w + l15][32 * c + quad * 8]);
#pragma unroll
      for (int j = 0; j < 8; ++j) {
        int d  = 16 * j + l15;
        int kk = (32 * c + quad * 8) ^ ((((unsigned)d >> 2) & 7) << 3);
        bf16x8 aw = ld_frag(&Wt[d][kk]);
        accO[j] = mfma16(aw, be, accO[j]);
      }
    }
  }

#pragma unroll
  for (int j = 0; j < 8; ++j) {
    float* op = O + ((size_t)b * SS + q0 + 16 * w + l15) * DQ + 16 * j + quad * 4;
    *(float4*)op = make_float4(accO[j][0], accO[j][1], accO[j][2], accO[j][3]);
  }
}

// ---------------------------------------------------------------------------
extern "C" void kernel_launch(void* const* d_in, const int* in_sizes, int n_in,
                              void* d_out, int out_size, void* d_ws, size_t ws_size,
                              hipStream_t stream) {
  const float* Q = (const float*)d_in[0];
  const float* K = (const float*)d_in[1];
  const float* V = (const float*)d_in[2];
  const int*   M = (const int*)d_in[3];
  float* O = (float*)d_out;

  const size_t msz = (size_t)NB * SS * 32 * sizeof(u64);             // 8 MiB
  const size_t fsz = (size_t)NB * SS * DQ * sizeof(unsigned short);  // 8 MiB
  const size_t lsz = (size_t)1 << 20;                                // 1 MiB (Lf)
  const size_t psz = (size_t)4 * NB * SS * DQ * sizeof(float);       // 64 MiB
  const size_t need = msz + 3 * fsz + lsz + psz;                     // 97 MiB

  zero_accum<<<dim3(NB), 256, 0, stream>>>(O);
  if (d_ws != nullptr && ws_size >= need) {
    u64* Mbp = (u64*)d_ws;
    unsigned short* Qf  = (unsigned short*)((char*)d_ws + msz);
    unsigned short* Kf  = (unsigned short*)((char*)d_ws + msz + fsz);
    unsigned short* Vtf = (unsigned short*)((char*)d_ws + msz + 2 * fsz);
    float* Lf = (float*)((char*)d_ws + msz + 3 * fsz);
    float* P  = (float*)((char*)d_ws + msz + 3 * fsz + lsz);
    compress_mask<<<dim3(NB, 512), 256, 0, stream>>>(M, Mbp);
    cast_qk<<<dim3(NB, 32, 2), 256, 0, stream>>>(Q, K, Qf, Kf);
    cast_vt<<<dim3(NB, 32), 256, 0, stream>>>(V, Vtf);
    pass1_frag<<<dim3(32, NB, 4), 256, 0, stream>>>(Qf, Kf, Mbp, O);
    linv_make<<<dim3(NB), 256, 0, stream>>>(O, Lf);
    pass2_wave<<<dim3(128, 4, NB), 64, 0, stream>>>(Qf, Kf, Vtf, Mbp, Lf, P);
    combine_O<<<dim3(NB, 32), 256, 0, stream>>>(P, O);
  } else {
    pass1_colsum<<<dim3(32, NB, 4), 256, 0, stream>>>(Q, K, M, O);
    combine_linv<<<dim3(NB, 8), 256, 0, stream>>>(O);
    pass2_out<<<dim3(32, NB), 256, 0, stream>>>(Q, K, V, M, O);
  }
}

// Round 9
// 506.673 us; speedup vs baseline: 1.4598x; 1.2705x over previous
//
#include <hip/hip_runtime.h>
#include <math.h>

#define NB 16
#define SS 2048
#define DQ 128
#define SCALE 0.08838834764831845f  // 1/sqrt(128)

typedef __bf16 bf16x8 __attribute__((ext_vector_type(8)));
typedef unsigned short ushort8_t __attribute__((ext_vector_type(8)));
typedef float floatx4 __attribute__((ext_vector_type(4)));

// fp32 -> bf16 round-to-nearest-even (finite randn inputs; no NaN path)
__device__ __forceinline__ unsigned short f2bf(float x) {
  unsigned int u = __float_as_uint(x);
  u += 0x7fffu + ((u >> 16) & 1u);
  return (unsigned short)(u >> 16);
}
union FragU { ushort8_t u; bf16x8 b; };
__device__ __forceinline__ bf16x8 ld_frag(const unsigned short* p) {
  FragU t; t.u = *(const ushort8_t*)p; return t.b;
}
__device__ __forceinline__ floatx4 mfma16(bf16x8 a, bf16x8 b, floatx4 c) {
  return __builtin_amdgcn_mfma_f32_16x16x32_bf16(a, b, c, 0, 0, 0);
}

// LDS-only barrier: waits DS ops, leaves global loads (vmcnt) IN FLIGHT.
__device__ __forceinline__ void bar_lds() {
  asm volatile("s_waitcnt lgkmcnt(0)\n\ts_barrier" ::: "memory");
}

// d_out scratch layout per batch b (each row = DQ floats):
//   rows q0..q0+15 for q0 in {0,64,...}: replicated Linv strips
//   rows 16..31: colsum accumulator (disjoint: strips at rows 0-15 of each
//   64-row group EXCEPT group 0 overlaps? No: strips live at rows 64m..64m+15;
//   m=0 strip is rows 0..15, colsum rows 16..31 — disjoint.)
// d_ws: [0,128Mi) E[b][q][k] bf16 = exp(masked_score).

// ---------------------------------------------------------------------------
__global__ void zero_accum(float* __restrict__ O) {
  float* p = O + (size_t)blockIdx.x * SS * DQ + 16 * DQ;
#pragma unroll
  for (int i = 0; i < 8; ++i) p[threadIdx.x + 256 * i] = 0.f;
}

// ---------------------------------------------------------------------------
// Pass 1 (round-1 structure, 2 K-tiles resident): colsum += sum_q exp(score),
// E persist. grid (16 kpairs, NB, 4 qchunks) = 1024 blocks, 256 thr, 3/CU.
// Per q-iteration: stage ONE Q-tile (same cost as round-1) but run 32 MFMAs
// against TWO resident K-tiles -> barrier-pair count and Q re-reads halve.
// Everything else (barrier pacing, prefetch, epilogue math, E layout) is the
// verified round-1 code applied per k-tile.
// ---------------------------------------------------------------------------
template<int WRITE_E>
__global__ __launch_bounds__(256, 3) void pass1_colsum(
    const float* __restrict__ Q, const float* __restrict__ K,
    const int* __restrict__ M, float* __restrict__ O,
    unsigned short* __restrict__ E)
{
  const int k0  = blockIdx.x * 128;       // two 64-wide k-tiles
  const int b   = blockIdx.y;
  const int qc  = blockIdx.z;
  const int tid = threadIdx.x;
  const int w = tid >> 6, lane = tid & 63, l15 = lane & 15, quad = lane >> 4;

  __shared__ unsigned short Kbf[128][136];  // 34.8 KB (resident, 2 tiles)
  __shared__ unsigned short Qbf[64][136];   // 17.4 KB (per q-iter; reduction
                                            //  buffer aliases here at the end)

  const float* Qb = Q + (size_t)b * SS * DQ;
  const float* Kb = K + (size_t)b * SS * DQ;
  const int*   Mb = M + (size_t)b * SS * SS;
  unsigned short* Eb = WRITE_E ? (E + (size_t)b * SS * SS) : nullptr;

  const int srow = tid >> 5;              // staging row base (this thread)
  const int sc4  = (tid & 31) * 4;        // staging col (floats)

  // stage K strip 128 x 128 -> bf16 (resident, both tiles)
#pragma unroll
  for (int r = 0; r < 16; ++r) {
    int row = srow + r * 8;
    float4 v = *(const float4*)(Kb + (size_t)(k0 + row) * DQ + sc4);
    *(ushort4*)&Kbf[row][sc4] = make_ushort4(f2bf(v.x), f2bf(v.y), f2bf(v.z), f2bf(v.w));
  }

  const int qlane = 16 * w + l15;         // wave-local q row within iter tile

  // prologue: prefetch q-tile 0 + its mask (both k-tiles) into registers
  float4 qreg[8];
  int4 mv_nxt[8];
  {
    const int q0 = qc * 512;
#pragma unroll
    for (int r = 0; r < 8; ++r)
      qreg[r] = *(const float4*)(Qb + (size_t)(q0 + srow + r * 8) * DQ + sc4);
#pragma unroll
    for (int t2 = 0; t2 < 2; ++t2)
#pragma unroll
      for (int i = 0; i < 4; ++i)
        mv_nxt[t2 * 4 + i] = *(const int4*)(Mb + (size_t)(q0 + qlane) * SS +
                                            k0 + t2 * 64 + 16 * i + quad * 4);
  }

  float colacc[32];
#pragma unroll
  for (int t = 0; t < 32; ++t) colacc[t] = 0.f;

  for (int qi = 0; qi < 8; ++qi) {
    bar_lds();  // prev Qbf readers done (1st iter: K-staging ds_writes drained)
    int4 mv[8];
#pragma unroll
    for (int t = 0; t < 8; ++t) mv[t] = mv_nxt[t];
    // store prefetched Q regs -> LDS (vmcnt waits are fine-grained here)
#pragma unroll
    for (int r = 0; r < 8; ++r) {
      float4 v = qreg[r];
      *(ushort4*)&Qbf[srow + r * 8][sc4] =
          make_ushort4(f2bf(v.x), f2bf(v.y), f2bf(v.z), f2bf(v.w));
    }
    bar_lds();  // Qbf ready; prefetch below flies across the next barrier
    if (qi < 7) {
      const int qn = qc * 512 + (qi + 1) * 64;
#pragma unroll
      for (int r = 0; r < 8; ++r)
        qreg[r] = *(const float4*)(Qb + (size_t)(qn + srow + r * 8) * DQ + sc4);
#pragma unroll
      for (int t2 = 0; t2 < 2; ++t2)
#pragma unroll
        for (int i = 0; i < 4; ++i)
          mv_nxt[t2 * 4 + i] = *(const int4*)(Mb + (size_t)(qn + qlane) * SS +
                                              k0 + t2 * 64 + 16 * i + quad * 4);
    }

    // QK against BOTH k-tiles: 32 MFMAs per barrier pair.
    // C row = k_local = 64*t2 + 16i + quad*4 + r, col = q = qlane
    floatx4 acc[8];
#pragma unroll
    for (int i = 0; i < 8; ++i) acc[i] = (floatx4){0.f, 0.f, 0.f, 0.f};
#pragma unroll
    for (int d0 = 0; d0 < DQ; d0 += 32) {
      bf16x8 bq = ld_frag(&Qbf[qlane][d0 + quad * 8]);
#pragma unroll
      for (int i = 0; i < 4; ++i) {
        bf16x8 ak0 = ld_frag(&Kbf[16 * i + l15][d0 + quad * 8]);
        acc[i] = mfma16(ak0, bq, acc[i]);
        bf16x8 ak1 = ld_frag(&Kbf[64 + 16 * i + l15][d0 + quad * 8]);
        acc[4 + i] = mfma16(ak1, bq, acc[4 + i]);
      }
    }
    // epilogue per k-tile: mask+exp, colsum accum, E write (round-1 math)
    const int qrow = qc * 512 + qi * 64 + qlane;
#pragma unroll
    for (int t2 = 0; t2 < 2; ++t2) {
#pragma unroll
      for (int i = 0; i < 4; ++i) {
        int4 mvw = mv[t2 * 4 + i];
        int mm[4] = {mvw.x, mvw.y, mvw.z, mvw.w};
        float ev[4];
#pragma unroll
        for (int r = 0; r < 4; ++r) {
          float s = mm[r] ? 1e-9f : acc[t2 * 4 + i][r] * SCALE;
          ev[r] = __expf(s);
          colacc[t2 * 16 + i * 4 + r] += ev[r];
        }
        if (WRITE_E) {
          *(ushort4*)(Eb + (size_t)qrow * SS + k0 + t2 * 64 + 16 * i + quad * 4) =
              make_ushort4(f2bf(ev[0]), f2bf(ev[1]), f2bf(ev[2]), f2bf(ev[3]));
        }
      }
    }
  }

  // reduce over the 16 q-lanes (l15 dimension)
#pragma unroll
  for (int t = 0; t < 32; ++t) {
    colacc[t] += __shfl_xor(colacc[t], 1, 64);
    colacc[t] += __shfl_xor(colacc[t], 2, 64);
    colacc[t] += __shfl_xor(colacc[t], 4, 64);
    colacc[t] += __shfl_xor(colacc[t], 8, 64);
  }
  bar_lds();   // all waves done reading Qbf -> safe to alias reduction buffer
  float* red = (float*)&Qbf[0][0];   // 4 x 128 floats = 2 KB, aliased on Qbf
  if (l15 == 0) {
#pragma unroll
    for (int t2 = 0; t2 < 2; ++t2)
#pragma unroll
      for (int i = 0; i < 4; ++i)
#pragma unroll
        for (int r = 0; r < 4; ++r)
          red[w * 128 + t2 * 64 + 16 * i + quad * 4 + r] =
              colacc[t2 * 16 + i * 4 + r];
  }
  bar_lds();
  if (tid < 128) {
    float s = red[tid] + red[128 + tid] + red[256 + tid] + red[384 + tid];
    atomicAdd(O + (size_t)b * SS * DQ + 16 * DQ + k0 + tid, s);
  }
}

// ---------------------------------------------------------------------------
// Combine: inv = 1/colsum; write replicated strips. grid (NB, 8), 256 thr.
// ---------------------------------------------------------------------------
__global__ void combine_linv(float* __restrict__ O) {
  const int b  = blockIdx.x;
  const int jb = blockIdx.y * 4;
  float* Ob = O + (size_t)b * SS * DQ;
#pragma unroll
  for (int it = 0; it < 8; ++it) {
    int k = threadIdx.x + 256 * it;
    float inv = 1.0f / Ob[16 * DQ + k];
#pragma unroll
    for (int j = 0; j < 4; ++j)
      Ob[(size_t)(64 * (jb + j)) * DQ + k] = inv;
  }
}

// ---------------------------------------------------------------------------
// Pass 2 (E-path, ROUND-1 VERBATIM — best measured variant): O[q][d] =
// sum_k E[q][k]*Linv[k]*V[k][d]. grid (32, NB) = 512 blocks, 256 thr.
// ---------------------------------------------------------------------------
__global__ __launch_bounds__(256, 2) void pass2_pv(
    const float* __restrict__ V, const unsigned short* __restrict__ E,
    float* __restrict__ O)
{
  const int b = blockIdx.y, q0 = blockIdx.x * 64;
  const int tid = threadIdx.x;
  const int w = tid >> 6, lane = tid & 63, l15 = lane & 15, quad = lane >> 4;

  __shared__ unsigned short Wt[128][72];   // 18.4 KB  [d][k^swz], Linv-folded V
  __shared__ float Li[SS];                 //  8.0 KB

  const float* Vb = V + (size_t)b * SS * DQ;
  const unsigned short* Erow =
      E + (size_t)b * SS * SS + (size_t)(q0 + 16 * w + l15) * SS;

  const int sc4 = (tid & 31) * 4;
  const int vk2 = (tid >> 5) * 2;   // V row-pair base for this thread (0..14)

  // preload replicated Linv strip from own territory (before any O write)
  {
    const float* src = O + ((size_t)b * SS + q0) * DQ;
#pragma unroll
    for (int r = 0; r < 2; ++r) {
      int idx = (tid + r * 256) * 4;
      *(float4*)&Li[idx] = *(const float4*)(src + idx);
    }
  }

  floatx4 accO[8];
#pragma unroll
  for (int j = 0; j < 8; ++j) accO[j] = (floatx4){0.f, 0.f, 0.f, 0.f};

  // prologue: prefetch k-tile 0 (V row-pairs + E fragments) into registers
  float4 vreg[8];
  FragU ef_nxt[2];
  {
#pragma unroll
    for (int r = 0; r < 4; ++r) {
      int k2 = vk2 + r * 16;
      vreg[2 * r]     = *(const float4*)(Vb + (size_t)(k2)     * DQ + sc4);
      vreg[2 * r + 1] = *(const float4*)(Vb + (size_t)(k2 + 1) * DQ + sc4);
    }
#pragma unroll
    for (int c = 0; c < 2; ++c)
      ef_nxt[c].u = *(const ushort8_t*)(Erow + 32 * c + quad * 8);
  }

  for (int k0 = 0; k0 < SS; k0 += 64) {
    bar_lds();  // prev iter's Wt readers done; Li ds_writes drained (1st iter)
    FragU ef[2] = {ef_nxt[0], ef_nxt[1]};

    // store prefetched V -> Wt (transposed, xor-swizzled), folding Linv[k]
#pragma unroll
    for (int r = 0; r < 4; ++r) {
      int k2 = vk2 + r * 16;
      float la = Li[k0 + k2], lb = Li[k0 + k2 + 1];
      float fa[4] = {vreg[2*r].x * la, vreg[2*r].y * la,
                     vreg[2*r].z * la, vreg[2*r].w * la};
      float fb[4] = {vreg[2*r+1].x * lb, vreg[2*r+1].y * lb,
                     vreg[2*r+1].z * lb, vreg[2*r+1].w * lb};
#pragma unroll
      for (int i = 0; i < 4; ++i) {
        int d  = sc4 + i;
        int kk = k2 ^ ((((unsigned)d >> 2) & 7) << 3);   // xor on k-bits 3..5
        *(ushort2*)&Wt[d][kk] = make_ushort2(f2bf(fa[i]), f2bf(fb[i]));
      }
    }
    bar_lds();  // Wt ready; the prefetch below stays in flight across iters

    if (k0 + 64 < SS) {
      const int kn = k0 + 64;
#pragma unroll
      for (int r = 0; r < 4; ++r) {
        int k2 = vk2 + r * 16;
        vreg[2 * r]     = *(const float4*)(Vb + (size_t)(kn + k2)     * DQ + sc4);
        vreg[2 * r + 1] = *(const float4*)(Vb + (size_t)(kn + k2 + 1) * DQ + sc4);
      }
#pragma unroll
      for (int c = 0; c < 2; ++c)
        ef_nxt[c].u = *(const ushort8_t*)(Erow + kn + 32 * c + quad * 8);
    }

    // PV: C row = d = 16j+quad*4+r, col = q = q0+16w+l15
#pragma unroll
    for (int c = 0; c < 2; ++c) {
      bf16x8 be = ef[c].b;
#pragma unroll
      for (int j = 0; j < 8; ++j) {
        int d  = 16 * j + l15;
        int kk = (32 * c + quad * 8) ^ ((((unsigned)d >> 2) & 7) << 3);
        bf16x8 aw = ld_frag(&Wt[d][kk]);
        accO[j] = mfma16(aw, be, accO[j]);
      }
    }
  }

  // write O: C row = d = 16j+quad*4+r, col = q = q0+16w+l15 -> float4 stores
#pragma unroll
  for (int j = 0; j < 8; ++j) {
    float* op = O + ((size_t)b * SS + q0 + 16 * w + l15) * DQ + 16 * j + quad * 4;
    *(float4*)op = make_float4(accO[j][0], accO[j][1], accO[j][2], accO[j][3]);
  }
}

// ---------------------------------------------------------------------------
// Pass 2 (fallback, no workspace): recompute QK + mask + exp, verified.
// ---------------------------------------------------------------------------
__global__ __launch_bounds__(256, 2) void pass2_out(
    const float* __restrict__ Q, const float* __restrict__ K,
    const float* __restrict__ V, const int* __restrict__ M,
    float* __restrict__ O)
{
  const int b = blockIdx.y, q0 = blockIdx.x * 64;
  const int tid = threadIdx.x;
  const int w = tid >> 6, lane = tid & 63, l15 = lane & 15, quad = lane >> 4;

  __shared__ unsigned short Kbf[64][136];
  __shared__ unsigned short Es[64][72];
  __shared__ unsigned short Wt[128][72];
  __shared__ float Li[SS];

  const float* Qb = Q + (size_t)b * SS * DQ;
  const float* Kb = K + (size_t)b * SS * DQ;
  const float* Vb = V + (size_t)b * SS * DQ;
  const int*   Mb = M + (size_t)b * SS * SS;

  const int srow = tid >> 5;
  const int sc4  = (tid & 31) * 4;

  {
    const float* src = O + ((size_t)b * SS + q0) * DQ;
#pragma unroll
    for (int r = 0; r < 2; ++r) {
      int idx = (tid + r * 256) * 4;
      *(float4*)&Li[idx] = *(const float4*)(src + idx);
    }
  }
  FragU qf[4];
  {
    const float* qrow = Qb + (size_t)(q0 + 16 * w + l15) * DQ;
#pragma unroll
    for (int i = 0; i < 4; ++i) {
      float4 a = *(const float4*)(qrow + 32 * i + quad * 8);
      float4 c = *(const float4*)(qrow + 32 * i + quad * 8 + 4);
      qf[i].u = (ushort8_t){f2bf(a.x), f2bf(a.y), f2bf(a.z), f2bf(a.w),
                            f2bf(c.x), f2bf(c.y), f2bf(c.z), f2bf(c.w)};
    }
  }

  floatx4 accO[8];
#pragma unroll
  for (int j = 0; j < 8; ++j) accO[j] = (floatx4){0.f, 0.f, 0.f, 0.f};

  const int* mrow = Mb + (size_t)(q0 + 16 * w + l15) * SS;

  float4 kreg[8], vreg[8];
  int4 mv_nxt[4];
  const int vk2 = (tid >> 5) * 2;
  {
#pragma unroll
    for (int r = 0; r < 8; ++r)
      kreg[r] = *(const float4*)(Kb + (size_t)(srow + r * 8) * DQ + sc4);
#pragma unroll
    for (int r = 0; r < 4; ++r) {
      int k2 = vk2 + r * 16;
      vreg[2 * r]     = *(const float4*)(Vb + (size_t)(k2)     * DQ + sc4);
      vreg[2 * r + 1] = *(const float4*)(Vb + (size_t)(k2 + 1) * DQ + sc4);
    }
#pragma unroll
    for (int j = 0; j < 4; ++j)
      mv_nxt[j] = *(const int4*)(mrow + 16 * j + quad * 4);
  }

  for (int k0 = 0; k0 < SS; k0 += 64) {
    bar_lds();
    int4 mv[4] = {mv_nxt[0], mv_nxt[1], mv_nxt[2], mv_nxt[3]};

#pragma unroll
    for (int r = 0; r < 8; ++r) {
      float4 v = kreg[r];
      *(ushort4*)&Kbf[srow + r * 8][sc4] =
          make_ushort4(f2bf(v.x), f2bf(v.y), f2bf(v.z), f2bf(v.w));
    }
#pragma unroll
    for (int r = 0; r < 4; ++r) {
      int k2 = vk2 + r * 16;
      float fa[4] = {vreg[2*r].x, vreg[2*r].y, vreg[2*r].z, vreg[2*r].w};
      float fb[4] = {vreg[2*r+1].x, vreg[2*r+1].y, vreg[2*r+1].z, vreg[2*r+1].w};
#pragma unroll
      for (int i = 0; i < 4; ++i) {
        int d  = sc4 + i;
        int kk = k2 ^ ((((unsigned)d >> 2) & 7) << 3);
        *(ushort2*)&Wt[d][kk] = make_ushort2(f2bf(fa[i]), f2bf(fb[i]));
      }
    }
    bar_lds();

    if (k0 + 64 < SS) {
      const int kn = k0 + 64;
#pragma unroll
      for (int r = 0; r < 8; ++r)
        kreg[r] = *(const float4*)(Kb + (size_t)(kn + srow + r * 8) * DQ + sc4);
#pragma unroll
      for (int r = 0; r < 4; ++r) {
        int k2 = vk2 + r * 16;
        vreg[2 * r]     = *(const float4*)(Vb + (size_t)(kn + k2)     * DQ + sc4);
        vreg[2 * r + 1] = *(const float4*)(Vb + (size_t)(kn + k2 + 1) * DQ + sc4);
      }
#pragma unroll
      for (int j = 0; j < 4; ++j)
        mv_nxt[j] = *(const int4*)(mrow + kn + 16 * j + quad * 4);
    }

    floatx4 acc[4];
#pragma unroll
    for (int j = 0; j < 4; ++j) acc[j] = (floatx4){0.f, 0.f, 0.f, 0.f};
#pragma unroll
    for (int i = 0; i < 4; ++i) {
      bf16x8 bq = qf[i].b;
#pragma unroll
      for (int j = 0; j < 4; ++j) {
        bf16x8 ak = ld_frag(&Kbf[16 * j + l15][32 * i + quad * 8]);
        acc[j] = mfma16(ak, bq, acc[j]);
      }
    }
#pragma unroll
    for (int j = 0; j < 4; ++j) {
      float4 liv = *(const float4*)&Li[k0 + 16 * j + quad * 4];
      float lv[4] = {liv.x, liv.y, liv.z, liv.w};
      int mm[4] = {mv[j].x, mv[j].y, mv[j].z, mv[j].w};
      unsigned short es[4];
#pragma unroll
      for (int r = 0; r < 4; ++r) {
        float s = mm[r] ? 1e-9f : acc[j][r] * SCALE;
        es[r] = f2bf(__expf(s) * lv[r]);
      }
      *(ushort4*)&Es[16 * w + l15][16 * j + quad * 4] =
          make_ushort4(es[0], es[1], es[2], es[3]);
    }
#pragma unroll
    for (int c = 0; c < 2; ++c) {
      bf16x8 be = ld_frag(&Es[16 * w + l15][32 * c + quad * 8]);
#pragma unroll
      for (int j = 0; j < 8; ++j) {
        int d  = 16 * j + l15;
        int kk = (32 * c + quad * 8) ^ ((((unsigned)d >> 2) & 7) << 3);
        bf16x8 aw = ld_frag(&Wt[d][kk]);
        accO[j] = mfma16(aw, be, accO[j]);
      }
    }
  }

#pragma unroll
  for (int j = 0; j < 8; ++j) {
    float* op = O + ((size_t)b * SS + q0 + 16 * w + l15) * DQ + 16 * j + quad * 4;
    *(float4*)op = make_float4(accO[j][0], accO[j][1], accO[j][2], accO[j][3]);
  }
}

// ---------------------------------------------------------------------------
extern "C" void kernel_launch(void* const* d_in, const int* in_sizes, int n_in,
                              void* d_out, int out_size, void* d_ws, size_t ws_size,
                              hipStream_t stream) {
  const float* Q = (const float*)d_in[0];
  const float* K = (const float*)d_in[1];
  const float* V = (const float*)d_in[2];
  const int*   M = (const int*)d_in[3];
  float* O = (float*)d_out;

  const size_t eneed = (size_t)NB * SS * SS * sizeof(unsigned short);  // 128 MiB

  zero_accum<<<dim3(NB), 256, 0, stream>>>(O);
  if (d_ws != nullptr && ws_size >= eneed) {
    unsigned short* E = (unsigned short*)d_ws;
    pass1_colsum<1><<<dim3(16, NB, 4), 256, 0, stream>>>(Q, K, M, O, E);
    combine_linv<<<dim3(NB, 8), 256, 0, stream>>>(O);
    pass2_pv<<<dim3(32, NB), 256, 0, stream>>>(V, E, O);
  } else {
    pass1_colsum<0><<<dim3(16, NB, 4), 256, 0, stream>>>(Q, K, M, O, nullptr);
    combine_linv<<<dim3(NB, 8), 256, 0, stream>>>(O);
    pass2_out<<<dim3(32, NB), 256, 0, stream>>>(Q, K, V, M, O);
  }
}